// Round 13
// baseline (3583.874 us; speedup 1.0000x reference)
//
#include <hip/hip_runtime.h>
#include <stdint.h>

typedef unsigned short u16;
typedef unsigned int u32;
typedef unsigned long long u64;
typedef __attribute__((ext_vector_type(8))) short bh8;        // 8 bf16 raw (4 VGPRs)
typedef __attribute__((ext_vector_type(8))) unsigned short u16x8;
typedef __attribute__((ext_vector_type(4))) float f32x4;
typedef __attribute__((ext_vector_type(4))) unsigned int u32x4;

#define B_ 32
#define T_ 1000
#define D_ 512
#define NG 2048   // 4*D

__device__ __forceinline__ float bf2f(u16 u) {
  union { unsigned int i; float f; } v; v.i = ((unsigned int)u) << 16; return v.f;
}
__device__ __forceinline__ u16 f2bf(float f) {
  union { float f; unsigned int i; } v; v.f = f;
  return (u16)((v.i + 0x7fffu + ((v.i >> 16) & 1u)) >> 16);   // RNE
}

// ---------------- weight transpose + f32->bf16 : dst[C][R] = src[R][C] ----------------
__global__ __launch_bounds__(256) void wtrans_k(const float* __restrict__ src,
                                                u16* __restrict__ dst, int R, int C) {
  __shared__ float tile[32][33];
  const int r0 = blockIdx.x * 32, c0 = blockIdx.y * 32;
  const int tid = threadIdx.x;
#pragma unroll
  for (int q = 0; q < 4; q++) {
    int idx = q * 256 + tid, rr = idx >> 5, cc = idx & 31;
    tile[rr][cc] = src[(size_t)(r0 + rr) * C + c0 + cc];
  }
  __syncthreads();
#pragma unroll
  for (int q = 0; q < 4; q++) {
    int idx = q * 256 + tid, cc = idx >> 5, rr = idx & 31;
    dst[(size_t)(c0 + cc) * R + r0 + rr] = f2bf(tile[rr][cc]);
  }
}

__global__ void bsum_k(const float* __restrict__ a, const float* __restrict__ b,
                       float* __restrict__ o) {
  int i = blockIdx.x * blockDim.x + threadIdx.x;
  if (i < NG) o[i] = a[i] + b[i];
}

// ---------------- x[:, 0:512] = emb[zi[b][t-1]] (0 for t==0), rows ordered (t,b) ----------------
__global__ __launch_bounds__(256) void embed_k(const int* __restrict__ zi,
                                               const float* __restrict__ emb,
                                               u16* __restrict__ x) {
  const int tid = threadIdx.x;
  const int r = blockIdx.x * 4 + (tid >> 6);        // (t*32+b), grid 8000
  const int d0 = (tid & 63) * 8;
  const int t = r >> 5, b = r & 31;
  u16x8 o;
  if (t == 0) {
#pragma unroll
    for (int i = 0; i < 8; i++) o[i] = 0;
  } else {
    const int zv = zi[b * T_ + t - 1];
    const float* s = emb + (size_t)zv * D_ + d0;
#pragma unroll
    for (int i = 0; i < 8; i++) o[i] = f2bf(s[i]);
  }
  *(u16x8*)(x + (size_t)r * 1024 + d0) = o;
}

// ---------------- x[:, 512:1024] = c[b][d][t] transposed (LDS tile) ----------------
__global__ __launch_bounds__(256) void ctrans_k(const float* __restrict__ c,
                                                u16* __restrict__ x) {
  __shared__ float tile[32][65];
  const int b = blockIdx.z, d0 = blockIdx.y * 32, t0 = blockIdx.x * 64;
  const int tid = threadIdx.x;
  const int dd = tid >> 3, tt0 = (tid & 7) * 8;
  const float* src = c + ((size_t)b * D_ + d0 + dd) * T_ + t0 + tt0;
#pragma unroll
  for (int i = 0; i < 8; i++) {
    int tt = tt0 + i;
    tile[dd][tt] = (t0 + tt < T_) ? src[i] : 0.f;
  }
  __syncthreads();
  const int tt = tid & 63, dq = tid >> 6;
  if (t0 + tt < T_) {
    u16x8 o;
#pragma unroll
    for (int i = 0; i < 8; i++) o[i] = f2bf(tile[dq * 8 + i][tt]);
    *(u16x8*)(x + ((size_t)(t0 + tt) * 32 + b) * 1024 + 512 + d0 + dq * 8) = o;
  }
}

// ---------------- bf16 MFMA GEMM: C[M,N] = act(A[M,K] @ Bt[N,K]^T + bias) ----------------
template <bool RELU, bool SCATTER>
__global__ __launch_bounds__(256, 2) void gemm_k(const u16* __restrict__ A,
                                                 const u16* __restrict__ Bt,
                                                 const float* __restrict__ bias,
                                                 void* __restrict__ Cout,
                                                 int M, int N, int K) {
  __shared__ u16 Al[128 * 40];
  __shared__ u16 Bl[128 * 40];
  const int tid = threadIdx.x;
  const int w = tid >> 6, l = tid & 63;
  const int row0 = blockIdx.x * 128, col0 = blockIdx.y * 128;
  const int wr = (w >> 1) * 64, wc = (w & 1) * 64;
  f32x4 acc[4][4];
  const f32x4 zero = {0.f, 0.f, 0.f, 0.f};
#pragma unroll
  for (int i = 0; i < 4; i++)
#pragma unroll
    for (int j = 0; j < 4; j++) acc[i][j] = zero;

  const int sm = tid >> 2;
  const int sk = (tid & 3) * 8;
  const u16* Ap = A + (size_t)(row0 + sm) * K + sk;
  const u16* Bp = Bt + (size_t)(col0 + sm) * K + sk;
  const size_t half = (size_t)64 * K;
  const int ldo = sm * 40 + sk;
  const int lr = l & 15, lk = (l >> 4) * 8;
  const int KT = K >> 5;

  bh8 a0 = *(const bh8*)Ap, a1 = *(const bh8*)(Ap + half);
  bh8 b0 = *(const bh8*)Bp, b1 = *(const bh8*)(Bp + half);

  for (int kt = 0; kt < KT; kt++) {
    const int kn = (kt + 1 < KT) ? (kt + 1) * 32 : 0;
    bh8 na0 = *(const bh8*)(Ap + kn), na1 = *(const bh8*)(Ap + half + kn);
    bh8 nb0 = *(const bh8*)(Bp + kn), nb1 = *(const bh8*)(Bp + half + kn);
    *(bh8*)(Al + ldo) = a0;
    *(bh8*)(Al + ldo + 64 * 40) = a1;
    *(bh8*)(Bl + ldo) = b0;
    *(bh8*)(Bl + ldo + 64 * 40) = b1;
    __syncthreads();
    bh8 af[4], bfr[4];
#pragma unroll
    for (int i = 0; i < 4; i++) af[i] = *(const bh8*)(Al + (wr + i * 16 + lr) * 40 + lk);
#pragma unroll
    for (int j = 0; j < 4; j++) bfr[j] = *(const bh8*)(Bl + (wc + j * 16 + lr) * 40 + lk);
#pragma unroll
    for (int i = 0; i < 4; i++)
#pragma unroll
      for (int j = 0; j < 4; j++)
        acc[i][j] = __builtin_amdgcn_mfma_f32_16x16x32_bf16(af[i], bfr[j], acc[i][j], 0, 0, 0);
    __syncthreads();
    a0 = na0; a1 = na1; b0 = nb0; b1 = nb1;
  }

  const int lrow = (l >> 4) * 4;
#pragma unroll
  for (int j = 0; j < 4; j++) {
    const int n = col0 + wc + j * 16 + lr;
    const float bv = bias[n];
#pragma unroll
    for (int i = 0; i < 4; i++) {
      const int r = row0 + wr + i * 16 + lrow;
      if (SCATTER) {  // out[b][n][t], r = b*T_+t
        const int bb = r / T_;
        const int t = r - bb * T_;
        f32x4 o;
#pragma unroll
        for (int e = 0; e < 4; e++) o[e] = acc[i][j][e] + bv;
        *(f32x4*)((float*)Cout + ((size_t)bb * N + n) * T_ + t) = o;
      } else {
#pragma unroll
        for (int e = 0; e < 4; e++) {
          float v = acc[i][j][e] + bv;
          if (RELU) v = v > 0.f ? v : 0.f;
          ((u16*)Cout)[(size_t)(r + e) * N + n] = f2bf(v);
        }
      }
    }
  }
}

// ---------------- LSTM scan v13: v12 + reader-only poll (writers never execute vmcnt) ----------------
// 8 groups x 4 batches (group = XCD via grid-256 round-robin); 16 active wgs/group; wg owns 32 h-dims.
// All waves: MFMA (builtin, gate = wave id) -> B1.
// Waves 0-1 (thr 0-127):  pointwise -> sc0 publish -> sc1 shadow store (plain, fire-and-forget)
//                          -> hs store -> xg prefetch(t+2). NO poll, NO vmcnt drain ever.
// Waves 2-3 (thr 128-255): poll 4 contiguous dwordx4 (16 dims, batch rb) with clean vmcnt,
//                          stage 2 b128 A-frag octets. Sticky agent-scope fallback after 512 rounds.
__global__ __launch_bounds__(256, 1) void scan_k(const u16* __restrict__ xg,   // [T*B][2048] rows (t,b)
                                                 const u16* __restrict__ Whht, // [2048][512]
                                                 u16* __restrict__ hs,         // [B][T][512]
                                                 u32* hbuf) {                  // fast[2][8][4][512] + shadow
  __shared__ u16 hstage[16 * 552];        // frag kk at kk*552; octet q at +q*136; row r at +r*8
  __shared__ float gl[4 * 132];           // [batch][gate*32 + dim]
  const int tid = threadIdx.x;
  const int wgid = blockIdx.x;
  const int grp = wgid & 7;               // XCD id under round-robin dispatch
  const int wgin = wgid >> 3;             // 0..31; only 0..15 active
  if (wgin >= 16) return;                 // idle wgs exit before any barrier
  const int D0 = wgin * 32;
  const int w = tid >> 6, l = tid & 63;
  const int lr = l & 15, lc = l >> 4;
  const int aoff = lc * 136 + lr * 8;     // A-frag u16 offset within a frag

  u32* fb = hbuf;                         // fast: [2][8][4][512] u32 = 128 KB
  u32* sb = hbuf + 32768;                 // shadow (device-visible via sc1), same layout

  // loop-invariant B fragments: wave w = gate w, tiles j=0,1 -> dims D0+16j..+15
  bh8 bfr[2][16];
#pragma unroll
  for (int j = 0; j < 2; j++) {
    const int c = w * 512 + D0 + j * 16 + lr;      // gate*512 + global dim
    const u16* wp = Whht + (size_t)c * 512 + lc * 8;
#pragma unroll
    for (int kk = 0; kk < 16; kk++) bfr[j][kk] = *(const bh8*)(wp + kk * 32);
  }

  // zero hstage (rows 4-15 of every frag stay zero forever)
  for (int i = tid; i < 16 * 552 / 2; i += 256) ((u32*)hstage)[i] = 0u;

  // writer mapping (threads 0-127): (batch pb, dim D0+pd)
  const int pb = tid >> 5, pd = tid & 31;
  const int gbat = grp * 4 + pb;
  const int gdim = D0 + pd;
  float ccv = 0.f;
  u16 xh0[4], xh1[4];                     // double-buffered gate inputs (t even / t odd)
  if (tid < 128) {
    const u16* xp0 = xg + (size_t)gbat * NG + gdim;                    // t = 0
    const u16* xp1 = xg + ((size_t)32 + gbat) * NG + gdim;             // t = 1
#pragma unroll
    for (int g = 0; g < 4; g++) { xh0[g] = xp0[g * 512]; xh1[g] = xp1[g * 512]; }
  }
  // reader mapping (threads 128-255): batch rb, 16 dims rd0..rd0+15 (2 octets)
  const int rtid = tid - 128;
  const int rb = rtid >> 5;
  const int rd0 = (rtid & 31) * 16;
  const int stidx = (rd0 >> 5) * 552 + ((rd0 >> 3) & 3) * 136 + rb * 8;  // u16 units
  bool slowmode = false;
  __syncthreads();

  auto step = [&](const int t, u16 (&xh)[4]) {
    // ---- gates = h_{t-1} @ Whh : 2 N-tiles per wave (gate w), K=512 ----
    f32x4 a0 = {0.f, 0.f, 0.f, 0.f}, a1 = a0;
#pragma unroll
    for (int kk = 0; kk < 16; kk++) {
      bh8 af = *(const bh8*)(hstage + kk * 552 + aoff);
      a0 = __builtin_amdgcn_mfma_f32_16x16x32_bf16(af, bfr[0][kk], a0, 0, 0, 0);
      a1 = __builtin_amdgcn_mfma_f32_16x16x32_bf16(af, bfr[1][kk], a1, 0, 0, 0);
    }
    if (lc == 0) {                        // C rows 0-3 = batches
#pragma unroll
      for (int e = 0; e < 4; e++) {
        gl[e * 132 + w * 32 + lr] = a0[e];
        gl[e * 132 + w * 32 + 16 + lr] = a1[e];
      }
    }
    // B1: LDS-only drain barrier
    asm volatile("s_waitcnt lgkmcnt(0)\n\ts_barrier" ::: "memory");
    __builtin_amdgcn_sched_barrier(0);

    if (tid < 128) {
      // ---- writers: pointwise (batch pb, dim D0+pd); everything fire-and-forget ----
      const float gi = gl[pb * 132 + pd]      + bf2f(xh[0]);
      const float gf = gl[pb * 132 + 32 + pd] + bf2f(xh[1]);
      const float gg = gl[pb * 132 + 64 + pd] + bf2f(xh[2]);
      const float go = gl[pb * 132 + 96 + pd] + bf2f(xh[3]);
      const float si = 1.f / (1.f + __expf(-gi));
      const float sf = 1.f / (1.f + __expf(-gf));
      const float tg = 1.f - 2.f / (__expf(2.f * gg) + 1.f);
      const float so = 1.f / (1.f + __expf(-go));
      ccv = sf * ccv + si * tg;
      const float hv = so * (1.f - 2.f / (__expf(2.f * ccv) + 1.f));
      const u16 hb = f2bf(hv);
      if (t + 1 < T_) {
        const u32 tagged = ((u32)(t + 1) << 16) | (u32)hb;
        const size_t idx = ((size_t)((t & 1) * 8 + grp) * 4 + pb) * 512 + gdim;
        // fast publish (XCD L2) then shadow publish (write-through past L2, device-visible)
        asm volatile("global_store_dword %0, %2, off sc0\n\t"
                     "global_store_dword %1, %2, off sc1"
                     :: "v"((u64)(uintptr_t)(fb + idx)), "v"((u64)(uintptr_t)(sb + idx)),
                        "v"(tagged) : "memory");
      }
      hs[((size_t)gbat * T_ + t) * 512 + gdim] = hb;
      if (t + 2 < T_) {                   // prefetch xg for t+2 into the buffer just consumed
        const u16* xp = xg + ((size_t)(t + 2) * 32 + gbat) * NG + gdim;
#pragma unroll
        for (int g = 0; g < 4; g++) xh[g] = xp[g * 512];
      }
    } else if (t + 1 < T_) {
      // ---- readers: poll 4 contiguous dwordx4 (16 dims, batch rb); clean vmcnt ----
      const u32 tag = (u32)(t + 1);
      const size_t base = ((size_t)((t & 1) * 8 + grp) * 4 + rb) * 512 + rd0;
      const u64 pa = (u64)(uintptr_t)(fb + base);
      u32x4 q0, q1, q2, q3;
      if (!slowmode) {
        int rounds = 0;
        for (;;) {
          asm volatile("global_load_dwordx4 %0, %4, off sc0\n\t"
                       "global_load_dwordx4 %1, %4, off offset:16 sc0\n\t"
                       "global_load_dwordx4 %2, %4, off offset:32 sc0\n\t"
                       "global_load_dwordx4 %3, %4, off offset:48 sc0\n\t"
                       "s_waitcnt vmcnt(0)"
                       : "=&v"(q0), "=&v"(q1), "=&v"(q2), "=&v"(q3) : "v"(pa) : "memory");
          u32 bad = 0;
#pragma unroll
          for (int e = 0; e < 4; e++)
            bad |= ((q0[e] >> 16) ^ tag) | ((q1[e] >> 16) ^ tag) |
                   ((q2[e] >> 16) ^ tag) | ((q3[e] >> 16) ^ tag);
          if (!__ballot(bad != 0u)) break;
          if (++rounds > 512) { slowmode = true; break; }
        }
      }
      if (slowmode) {                     // placement-independent fallback (device scope)
        const u64* sp = (const u64*)(sb + base);
        for (;;) {
          u32x4 v[4];
#pragma unroll
          for (int i = 0; i < 8; i++) {
            u64 s = __hip_atomic_load(sp + i, __ATOMIC_RELAXED, __HIP_MEMORY_SCOPE_AGENT);
            v[i >> 1][(i & 1) * 2] = (u32)s;
            v[i >> 1][(i & 1) * 2 + 1] = (u32)(s >> 32);
          }
          u32 bad = 0;
#pragma unroll
          for (int i = 0; i < 4; i++)
#pragma unroll
            for (int e = 0; e < 4; e++) bad |= (v[i][e] >> 16) ^ tag;
          if (!__ballot(bad != 0u)) { q0 = v[0]; q1 = v[1]; q2 = v[2]; q3 = v[3]; break; }
        }
      }
      // ---- stage 2 octets as MFMA A-frags: two 16B LDS writes ----
      u32x4 w0, w1;
      w0[0] = (q0[0] & 0xffffu) | (q0[1] << 16);
      w0[1] = (q0[2] & 0xffffu) | (q0[3] << 16);
      w0[2] = (q1[0] & 0xffffu) | (q1[1] << 16);
      w0[3] = (q1[2] & 0xffffu) | (q1[3] << 16);
      w1[0] = (q2[0] & 0xffffu) | (q2[1] << 16);
      w1[1] = (q2[2] & 0xffffu) | (q2[3] << 16);
      w1[2] = (q3[0] & 0xffffu) | (q3[1] << 16);
      w1[3] = (q3[2] & 0xffffu) | (q3[3] << 16);
      *(u32x4*)(hstage + stidx) = w0;
      *(u32x4*)(hstage + stidx + 136) = w1;
    }
    // B2: LDS-only drain barrier — hstage(t) ready; globals stay in flight
    asm volatile("s_waitcnt lgkmcnt(0)\n\ts_barrier" ::: "memory");
    __builtin_amdgcn_sched_barrier(0);
  };

  for (int t = 0; t < T_; t += 2) {
    step(t, xh0);
    step(t + 1, xh1);
  }
}

extern "C" void kernel_launch(void* const* d_in, const int* in_sizes, int n_in,
                              void* d_out, int out_size, void* d_ws, size_t ws_size,
                              hipStream_t stream) {
  const int*   zi    = (const int*)d_in[0];
  const float* c     = (const float*)d_in[1];
  const float* emb   = (const float*)d_in[2];
  const float* W1    = (const float*)d_in[3];
  const float* b1    = (const float*)d_in[4];
  const float* W2    = (const float*)d_in[5];
  const float* b2    = (const float*)d_in[6];
  const float* W_ih  = (const float*)d_in[7];
  const float* b_ih  = (const float*)d_in[8];
  const float* W_hh  = (const float*)d_in[9];
  const float* b_hh  = (const float*)d_in[10];
  const float* W_out = (const float*)d_in[11];
  const float* b_out = (const float*)d_in[12];
  float* out = (float*)d_out;
  char* ws = (char*)d_ws;

  const size_t x_off   = 0;
  const size_t xg_off  = 65536000;
  const size_t pre_off = 32768000;
  const size_t w_off   = xg_off + 131072000;
  u16* xb    = (u16*)(ws + x_off);
  u16* hsb   = (u16*)(ws + x_off);
  u16* preb  = (u16*)(ws + pre_off);
  u16* xgb   = (u16*)(ws + xg_off);
  u16* h1b   = (u16*)(ws + xg_off);
  u16* W1t   = (u16*)(ws + w_off);           // [512][1024]
  u16* W2t   = W1t + 512 * 1024;             // [512][512]
  u16* Wiht  = W2t + 512 * 512;              // [2048][512]
  u16* Whht  = Wiht + 2048 * 512;            // [2048][512]
  u16* Woutt = Whht + 2048 * 512;            // [512][512]
  float* bsum = (float*)(Woutt + 512 * 512);
  u32* hbuf  = (u32*)(bsum + NG);            // fast 128KB + shadow 128KB

  hipMemsetAsync(hbuf, 0, 2 * 32768 * sizeof(u32), stream);

  wtrans_k<<<dim3(32, 16), 256, 0, stream>>>(W1, W1t, 1024, 512);
  wtrans_k<<<dim3(16, 16), 256, 0, stream>>>(W2, W2t, 512, 512);
  wtrans_k<<<dim3(16, 64), 256, 0, stream>>>(W_ih, Wiht, 512, 2048);
  wtrans_k<<<dim3(16, 64), 256, 0, stream>>>(W_hh, Whht, 512, 2048);
  wtrans_k<<<dim3(16, 16), 256, 0, stream>>>(W_out, Woutt, 512, 512);
  bsum_k<<<8, 256, 0, stream>>>(b_ih, b_hh, bsum);
  embed_k<<<8000, 256, 0, stream>>>(zi, emb, xb);
  ctrans_k<<<dim3(16, 16, 32), 256, 0, stream>>>(c, xb);

  gemm_k<true,  false><<<dim3(250, 4),  256, 0, stream>>>(xb,   W1t,   b1,    h1b,  32000, 512,  1024);
  gemm_k<false, false><<<dim3(250, 4),  256, 0, stream>>>(h1b,  W2t,   b2,    preb, 32000, 512,  512);
  gemm_k<false, false><<<dim3(250, 16), 256, 0, stream>>>(preb, Wiht,  bsum,  xgb,  32000, 2048, 512);
  scan_k<<<256, 256, 0, stream>>>(xgb, Whht, hsb, hbuf);
  gemm_k<false, true ><<<dim3(250, 4),  256, 0, stream>>>(hsb,  Woutt, b_out, out,  32000, 512,  512);
}

// Round 14
// 2771.053 us; speedup vs baseline: 1.2933x; 1.2933x over previous
//
#include <hip/hip_runtime.h>
#include <stdint.h>

typedef unsigned short u16;
typedef unsigned int u32;
typedef unsigned long long u64;
typedef __attribute__((ext_vector_type(8))) short bh8;        // 8 bf16 raw (4 VGPRs)
typedef __attribute__((ext_vector_type(8))) unsigned short u16x8;
typedef __attribute__((ext_vector_type(4))) float f32x4;
typedef __attribute__((ext_vector_type(4))) unsigned int u32x4;

#define B_ 32
#define T_ 1000
#define D_ 512
#define NG 2048   // 4*D

__device__ __forceinline__ float bf2f(u16 u) {
  union { unsigned int i; float f; } v; v.i = ((unsigned int)u) << 16; return v.f;
}
__device__ __forceinline__ u16 f2bf(float f) {
  union { float f; unsigned int i; } v; v.f = f;
  return (u16)((v.i + 0x7fffu + ((v.i >> 16) & 1u)) >> 16);   // RNE
}

// ---------------- weight transpose + f32->bf16 : dst[C][R] = src[R][C] ----------------
__global__ __launch_bounds__(256) void wtrans_k(const float* __restrict__ src,
                                                u16* __restrict__ dst, int R, int C) {
  __shared__ float tile[32][33];
  const int r0 = blockIdx.x * 32, c0 = blockIdx.y * 32;
  const int tid = threadIdx.x;
#pragma unroll
  for (int q = 0; q < 4; q++) {
    int idx = q * 256 + tid, rr = idx >> 5, cc = idx & 31;
    tile[rr][cc] = src[(size_t)(r0 + rr) * C + c0 + cc];
  }
  __syncthreads();
#pragma unroll
  for (int q = 0; q < 4; q++) {
    int idx = q * 256 + tid, cc = idx >> 5, rr = idx & 31;
    dst[(size_t)(c0 + cc) * R + r0 + rr] = f2bf(tile[rr][cc]);
  }
}

__global__ void bsum_k(const float* __restrict__ a, const float* __restrict__ b,
                       float* __restrict__ o) {
  int i = blockIdx.x * blockDim.x + threadIdx.x;
  if (i < NG) o[i] = a[i] + b[i];
}

// ---------------- x[:, 0:512] = emb[zi[b][t-1]] (0 for t==0), rows ordered (t,b) ----------------
__global__ __launch_bounds__(256) void embed_k(const int* __restrict__ zi,
                                               const float* __restrict__ emb,
                                               u16* __restrict__ x) {
  const int tid = threadIdx.x;
  const int r = blockIdx.x * 4 + (tid >> 6);        // (t*32+b), grid 8000
  const int d0 = (tid & 63) * 8;
  const int t = r >> 5, b = r & 31;
  u16x8 o;
  if (t == 0) {
#pragma unroll
    for (int i = 0; i < 8; i++) o[i] = 0;
  } else {
    const int zv = zi[b * T_ + t - 1];
    const float* s = emb + (size_t)zv * D_ + d0;
#pragma unroll
    for (int i = 0; i < 8; i++) o[i] = f2bf(s[i]);
  }
  *(u16x8*)(x + (size_t)r * 1024 + d0) = o;
}

// ---------------- x[:, 512:1024] = c[b][d][t] transposed (LDS tile) ----------------
__global__ __launch_bounds__(256) void ctrans_k(const float* __restrict__ c,
                                                u16* __restrict__ x) {
  __shared__ float tile[32][65];
  const int b = blockIdx.z, d0 = blockIdx.y * 32, t0 = blockIdx.x * 64;
  const int tid = threadIdx.x;
  const int dd = tid >> 3, tt0 = (tid & 7) * 8;
  const float* src = c + ((size_t)b * D_ + d0 + dd) * T_ + t0 + tt0;
#pragma unroll
  for (int i = 0; i < 8; i++) {
    int tt = tt0 + i;
    tile[dd][tt] = (t0 + tt < T_) ? src[i] : 0.f;
  }
  __syncthreads();
  const int tt = tid & 63, dq = tid >> 6;
  if (t0 + tt < T_) {
    u16x8 o;
#pragma unroll
    for (int i = 0; i < 8; i++) o[i] = f2bf(tile[dq * 8 + i][tt]);
    *(u16x8*)(x + ((size_t)(t0 + tt) * 32 + b) * 1024 + 512 + d0 + dq * 8) = o;
  }
}

// ---------------- bf16 MFMA GEMM: C[M,N] = act(A[M,K] @ Bt[N,K]^T + bias) ----------------
template <bool RELU, bool SCATTER>
__global__ __launch_bounds__(256, 2) void gemm_k(const u16* __restrict__ A,
                                                 const u16* __restrict__ Bt,
                                                 const float* __restrict__ bias,
                                                 void* __restrict__ Cout,
                                                 int M, int N, int K) {
  __shared__ u16 Al[128 * 40];
  __shared__ u16 Bl[128 * 40];
  const int tid = threadIdx.x;
  const int w = tid >> 6, l = tid & 63;
  const int row0 = blockIdx.x * 128, col0 = blockIdx.y * 128;
  const int wr = (w >> 1) * 64, wc = (w & 1) * 64;
  f32x4 acc[4][4];
  const f32x4 zero = {0.f, 0.f, 0.f, 0.f};
#pragma unroll
  for (int i = 0; i < 4; i++)
#pragma unroll
    for (int j = 0; j < 4; j++) acc[i][j] = zero;

  const int sm = tid >> 2;
  const int sk = (tid & 3) * 8;
  const u16* Ap = A + (size_t)(row0 + sm) * K + sk;
  const u16* Bp = Bt + (size_t)(col0 + sm) * K + sk;
  const size_t half = (size_t)64 * K;
  const int ldo = sm * 40 + sk;
  const int lr = l & 15, lk = (l >> 4) * 8;
  const int KT = K >> 5;

  bh8 a0 = *(const bh8*)Ap, a1 = *(const bh8*)(Ap + half);
  bh8 b0 = *(const bh8*)Bp, b1 = *(const bh8*)(Bp + half);

  for (int kt = 0; kt < KT; kt++) {
    const int kn = (kt + 1 < KT) ? (kt + 1) * 32 : 0;
    bh8 na0 = *(const bh8*)(Ap + kn), na1 = *(const bh8*)(Ap + half + kn);
    bh8 nb0 = *(const bh8*)(Bp + kn), nb1 = *(const bh8*)(Bp + half + kn);
    *(bh8*)(Al + ldo) = a0;
    *(bh8*)(Al + ldo + 64 * 40) = a1;
    *(bh8*)(Bl + ldo) = b0;
    *(bh8*)(Bl + ldo + 64 * 40) = b1;
    __syncthreads();
    bh8 af[4], bfr[4];
#pragma unroll
    for (int i = 0; i < 4; i++) af[i] = *(const bh8*)(Al + (wr + i * 16 + lr) * 40 + lk);
#pragma unroll
    for (int j = 0; j < 4; j++) bfr[j] = *(const bh8*)(Bl + (wc + j * 16 + lr) * 40 + lk);
#pragma unroll
    for (int i = 0; i < 4; i++)
#pragma unroll
      for (int j = 0; j < 4; j++)
        acc[i][j] = __builtin_amdgcn_mfma_f32_16x16x32_bf16(af[i], bfr[j], acc[i][j], 0, 0, 0);
    __syncthreads();
    a0 = na0; a1 = na1; b0 = nb0; b1 = nb1;
  }

  const int lrow = (l >> 4) * 4;
#pragma unroll
  for (int j = 0; j < 4; j++) {
    const int n = col0 + wc + j * 16 + lr;
    const float bv = bias[n];
#pragma unroll
    for (int i = 0; i < 4; i++) {
      const int r = row0 + wr + i * 16 + lrow;
      if (SCATTER) {  // out[b][n][t], r = b*T_+t
        const int bb = r / T_;
        const int t = r - bb * T_;
        f32x4 o;
#pragma unroll
        for (int e = 0; e < 4; e++) o[e] = acc[i][j][e] + bv;
        *(f32x4*)((float*)Cout + ((size_t)bb * N + n) * T_ + t) = o;
      } else {
#pragma unroll
        for (int e = 0; e < 4; e++) {
          float v = acc[i][j][e] + bv;
          if (RELU) v = v > 0.f ? v : 0.f;
          ((u16*)Cout)[(size_t)(r + e) * N + n] = f2bf(v);
        }
      }
    }
  }
}

// ---------------- LSTM scan v14: gate-packed waves, single barrier per step ----------------
// 8 groups x 4 batches (group = XCD via grid-256 round-robin); 16 active wgs/group; wg owns 32 dims.
// Wave w owns dims D0+8w..+7 and computes ALL FOUR gates for them:
//   tile0 cols = {gate0 x 8dims, gate1 x 8dims}, tile1 = {gate2, gate3}.
// After MFMA, shfl_xor(8) gives lanes 0-15 the full (i,f,g,o) quad in-register:
//   lanes 0-7 -> batches 0-1, lanes 8-15 -> batches 2-3 (2 LSTM units/lane).
// Pointwise+publish run right after the wave's own MFMA — no inter-wave exchange, no B1.
// hstage double-buffered -> ONE lgkm-only barrier per step. Poll/stage = v12 (best measured).
__global__ __launch_bounds__(256, 1) void scan_k(const u16* __restrict__ xg,   // [T*B][2048] rows (t,b)
                                                 const u16* __restrict__ Whht, // [2048][512]
                                                 u16* __restrict__ hs,         // [B][T][512]
                                                 u32* hbuf) {                  // fast[2][8][4][512] + shadow
  __shared__ u16 hstage[2][16 * 552];     // [buf][frag kk*552 + octet*136 + row*8]
  const int tid = threadIdx.x;
  const int wgid = blockIdx.x;
  const int grp = wgid & 7;               // XCD id under round-robin dispatch
  const int wgin = wgid >> 3;             // 0..31; only 0..15 active
  if (wgin >= 16) return;                 // idle wgs exit before any barrier
  const int D0 = wgin * 32;
  const int w = tid >> 6, l = tid & 63;
  const int lr = l & 15, lc = l >> 4;
  const int aoff = lc * 136 + lr * 8;     // A-frag u16 offset within a frag
  const int Dw = D0 + 8 * w;              // this wave's 8 dims

  u32* fb = hbuf;                         // fast: [2][8][4][512] u32 = 128 KB
  u32* sb = hbuf + 32768;                 // shadow (device-visible via sc1), same layout

  // loop-invariant B fragments: tile j cols = {gate 2j x dims Dw..+7, gate 2j+1 x dims Dw..+7}
  bh8 bfr[2][16];
#pragma unroll
  for (int j = 0; j < 2; j++) {
    const int gate = 2 * j + (lr >> 3);
    const u16* wp = Whht + (size_t)(gate * 512 + Dw + (lr & 7)) * 512 + lc * 8;
#pragma unroll
    for (int kk = 0; kk < 16; kk++) bfr[j][kk] = *(const bh8*)(wp + kk * 32);
  }

  // zero both hstage buffers (rows 4+ of every frag stay zero forever)
  for (int i = tid; i < 8832; i += 256) ((u32*)hstage)[i] = 0u;

  // writer mapping (lanes 0-15 of each wave): dim gdim = Dw + (l&7);
  // lanes 0-7 -> batches {0,1}, lanes 8-15 -> batches {2,3}
  const int gdim = Dw + (l & 7);
  const int eb = (l >> 3) & 1 ? 2 : 0;    // batch base for this lane (valid for l<16)
  float cc2[2] = {0.f, 0.f};
  u16 xh0[2][4], xh1[2][4];               // [batch j][gate], double-buffered (t even/odd)
  if (l < 16) {
#pragma unroll
    for (int j = 0; j < 2; j++) {
      const int gb = grp * 4 + eb + j;
#pragma unroll
      for (int g = 0; g < 4; g++) {
        xh0[j][g] = xg[(size_t)gb * NG + g * 512 + gdim];              // t = 0
        xh1[j][g] = xg[((size_t)32 + gb) * NG + g * 512 + gdim];       // t = 1
      }
    }
  }
  // reader mapping (all 256 threads): batch rb, dim octet rd0..rd0+7
  const int rb = tid >> 6;
  const int rd0 = (tid & 63) * 8;
  const int stbase = (rd0 >> 5) * 552 + ((rd0 >> 3) & 3) * 136 + rb * 8;  // u16 units
  bool slowmode = false;
  __syncthreads();

  auto step = [&](const int t, u16 (&xh)[2][4]) {
    const int cur = t & 1;
    // ---- gates: 2 tiles per wave (4 gates x own 8 dims), K=512, A = hstage[cur] ----
    f32x4 a0 = {0.f, 0.f, 0.f, 0.f}, a1 = a0;
#pragma unroll
    for (int kk = 0; kk < 16; kk++) {
      bh8 af = *(const bh8*)(&hstage[cur][kk * 552 + aoff]);
      a0 = __builtin_amdgcn_mfma_f32_16x16x32_bf16(af, bfr[0][kk], a0, 0, 0, 0);
      a1 = __builtin_amdgcn_mfma_f32_16x16x32_bf16(af, bfr[1][kk], a1, 0, 0, 0);
    }
    // ---- in-wave gate exchange: lane d <-> lane d+8 ----
    f32x4 b0, b1;
#pragma unroll
    for (int e = 0; e < 4; e++) {
      b0[e] = __shfl_xor(a0[e], 8);
      b1[e] = __shfl_xor(a1[e], 8);
    }
    if (l < 16) {
      // lanes 0-7: a0=i, b0=f, a1=g, b1=o ; lanes 8-15: roles swapped
      const bool hi = (l >> 3) & 1;
      const f32x4 vi = hi ? b0 : a0, vf = hi ? a0 : b0;
      const f32x4 vg = hi ? b1 : a1, vo = hi ? a1 : b1;
      u16 hbv[2];
#pragma unroll
      for (int j = 0; j < 2; j++) {
        const int e = eb + j;
        const float gi = vi[e] + bf2f(xh[j][0]);
        const float gf = vf[e] + bf2f(xh[j][1]);
        const float gg = vg[e] + bf2f(xh[j][2]);
        const float go = vo[e] + bf2f(xh[j][3]);
        const float si = 1.f / (1.f + __expf(-gi));
        const float sf = 1.f / (1.f + __expf(-gf));
        const float tg = 1.f - 2.f / (__expf(2.f * gg) + 1.f);
        const float so = 1.f / (1.f + __expf(-go));
        cc2[j] = sf * cc2[j] + si * tg;
        hbv[j] = f2bf(so * (1.f - 2.f / (__expf(2.f * cc2[j]) + 1.f)));
      }
      if (t + 1 < T_) {                   // publish both batches: sc0 fast + sc1 shadow
        const u32 tag = (u32)(t + 1) << 16;
#pragma unroll
        for (int j = 0; j < 2; j++) {
          const size_t idx = ((size_t)(cur * 8 + grp) * 4 + eb + j) * 512 + gdim;
          const u32 tv = tag | (u32)hbv[j];
          asm volatile("global_store_dword %0, %2, off sc0\n\t"
                       "global_store_dword %1, %2, off sc1"
                       :: "v"((u64)(uintptr_t)(fb + idx)), "v"((u64)(uintptr_t)(sb + idx)),
                          "v"(tv) : "memory");
        }
      }
#pragma unroll
      for (int j = 0; j < 2; j++)
        hs[((size_t)(grp * 4 + eb + j) * T_ + t) * 512 + gdim] = hbv[j];
      if (t + 2 < T_) {                   // prefetch xg for t+2 into the buffer just consumed
#pragma unroll
        for (int j = 0; j < 2; j++) {
          const u16* xp = xg + ((size_t)(t + 2) * 32 + grp * 4 + eb + j) * NG + gdim;
#pragma unroll
          for (int g = 0; g < 4; g++) xh[j][g] = xp[g * 512];
        }
      }
    }
    if (t + 1 < T_) {
      // ---- all threads: poll 2 contiguous dwordx4 (dims rd0..rd0+7, batch rb) ----
      const u32 tag = (u32)(t + 1);
      const size_t base = ((size_t)(cur * 8 + grp) * 4 + rb) * 512 + rd0;
      const u64 pa = (u64)(uintptr_t)(fb + base);
      u32x4 qa, qb;
      if (!slowmode) {
        int rounds = 0;
        for (;;) {
          asm volatile("global_load_dwordx4 %0, %2, off sc0\n\t"
                       "global_load_dwordx4 %1, %2, off offset:16 sc0\n\t"
                       "s_waitcnt vmcnt(0)"
                       : "=&v"(qa), "=&v"(qb) : "v"(pa) : "memory");
          const bool bad = (qa[0] >> 16) != tag || (qa[1] >> 16) != tag ||
                           (qa[2] >> 16) != tag || (qa[3] >> 16) != tag ||
                           (qb[0] >> 16) != tag || (qb[1] >> 16) != tag ||
                           (qb[2] >> 16) != tag || (qb[3] >> 16) != tag;
          if (!__ballot(bad)) break;
          if (++rounds > 512) { slowmode = true; break; }
        }
      }
      if (slowmode) {                     // placement-independent fallback (device scope)
        const u64* sp = (const u64*)(sb + base);
        for (;;) {
          u64 s0 = __hip_atomic_load(sp + 0, __ATOMIC_RELAXED, __HIP_MEMORY_SCOPE_AGENT);
          u64 s1 = __hip_atomic_load(sp + 1, __ATOMIC_RELAXED, __HIP_MEMORY_SCOPE_AGENT);
          u64 s2 = __hip_atomic_load(sp + 2, __ATOMIC_RELAXED, __HIP_MEMORY_SCOPE_AGENT);
          u64 s3 = __hip_atomic_load(sp + 3, __ATOMIC_RELAXED, __HIP_MEMORY_SCOPE_AGENT);
          qa[0] = (u32)s0; qa[1] = (u32)(s0 >> 32);
          qa[2] = (u32)s1; qa[3] = (u32)(s1 >> 32);
          qb[0] = (u32)s2; qb[1] = (u32)(s2 >> 32);
          qb[2] = (u32)s3; qb[3] = (u32)(s3 >> 32);
          const bool bad = (qa[0] >> 16) != tag || (qa[1] >> 16) != tag ||
                           (qa[2] >> 16) != tag || (qa[3] >> 16) != tag ||
                           (qb[0] >> 16) != tag || (qb[1] >> 16) != tag ||
                           (qb[2] >> 16) != tag || (qb[3] >> 16) != tag;
          if (!__ballot(bad)) break;
        }
      }
      // ---- stage as MFMA A-frag octet into hstage[cur^1]: one 16B LDS write ----
      u32x4 pw;
      pw[0] = (qa[0] & 0xffffu) | (qa[1] << 16);
      pw[1] = (qa[2] & 0xffffu) | (qa[3] << 16);
      pw[2] = (qb[0] & 0xffffu) | (qb[1] << 16);
      pw[3] = (qb[2] & 0xffffu) | (qb[3] << 16);
      *(u32x4*)(&hstage[cur ^ 1][stbase]) = pw;
    }
    // single per-step barrier: LDS-only drain (globals stay in flight)
    asm volatile("s_waitcnt lgkmcnt(0)\n\ts_barrier" ::: "memory");
    __builtin_amdgcn_sched_barrier(0);
  };

  for (int t = 0; t < T_; t += 2) {
    step(t, xh0);
    step(t + 1, xh1);
  }
}

extern "C" void kernel_launch(void* const* d_in, const int* in_sizes, int n_in,
                              void* d_out, int out_size, void* d_ws, size_t ws_size,
                              hipStream_t stream) {
  const int*   zi    = (const int*)d_in[0];
  const float* c     = (const float*)d_in[1];
  const float* emb   = (const float*)d_in[2];
  const float* W1    = (const float*)d_in[3];
  const float* b1    = (const float*)d_in[4];
  const float* W2    = (const float*)d_in[5];
  const float* b2    = (const float*)d_in[6];
  const float* W_ih  = (const float*)d_in[7];
  const float* b_ih  = (const float*)d_in[8];
  const float* W_hh  = (const float*)d_in[9];
  const float* b_hh  = (const float*)d_in[10];
  const float* W_out = (const float*)d_in[11];
  const float* b_out = (const float*)d_in[12];
  float* out = (float*)d_out;
  char* ws = (char*)d_ws;

  const size_t x_off   = 0;
  const size_t xg_off  = 65536000;
  const size_t pre_off = 32768000;
  const size_t w_off   = xg_off + 131072000;
  u16* xb    = (u16*)(ws + x_off);
  u16* hsb   = (u16*)(ws + x_off);
  u16* preb  = (u16*)(ws + pre_off);
  u16* xgb   = (u16*)(ws + xg_off);
  u16* h1b   = (u16*)(ws + xg_off);
  u16* W1t   = (u16*)(ws + w_off);           // [512][1024]
  u16* W2t   = W1t + 512 * 1024;             // [512][512]
  u16* Wiht  = W2t + 512 * 512;              // [2048][512]
  u16* Whht  = Wiht + 2048 * 512;            // [2048][512]
  u16* Woutt = Whht + 2048 * 512;            // [512][512]
  float* bsum = (float*)(Woutt + 512 * 512);
  u32* hbuf  = (u32*)(bsum + NG);            // fast 128KB + shadow 128KB

  hipMemsetAsync(hbuf, 0, 2 * 32768 * sizeof(u32), stream);

  wtrans_k<<<dim3(32, 16), 256, 0, stream>>>(W1, W1t, 1024, 512);
  wtrans_k<<<dim3(16, 16), 256, 0, stream>>>(W2, W2t, 512, 512);
  wtrans_k<<<dim3(16, 64), 256, 0, stream>>>(W_ih, Wiht, 512, 2048);
  wtrans_k<<<dim3(16, 64), 256, 0, stream>>>(W_hh, Whht, 512, 2048);
  wtrans_k<<<dim3(16, 16), 256, 0, stream>>>(W_out, Woutt, 512, 512);
  bsum_k<<<8, 256, 0, stream>>>(b_ih, b_hh, bsum);
  embed_k<<<8000, 256, 0, stream>>>(zi, emb, xb);
  ctrans_k<<<dim3(16, 16, 32), 256, 0, stream>>>(c, xb);

  gemm_k<true,  false><<<dim3(250, 4),  256, 0, stream>>>(xb,   W1t,   b1,    h1b,  32000, 512,  1024);
  gemm_k<false, false><<<dim3(250, 4),  256, 0, stream>>>(h1b,  W2t,   b2,    preb, 32000, 512,  512);
  gemm_k<false, false><<<dim3(250, 16), 256, 0, stream>>>(preb, Wiht,  bsum,  xgb,  32000, 2048, 512);
  scan_k<<<256, 256, 0, stream>>>(xgb, Whht, hsb, hbuf);
  gemm_k<false, true ><<<dim3(250, 4),  256, 0, stream>>>(hsb,  Woutt, b_out, out,  32000, 512,  512);
}